// Round 8
// baseline (66.837 us; speedup 1.0000x reference)
//
#include <hip/hip_runtime.h>
#include <math.h>

namespace {
constexpr int L1 = 13;   // 12 history layers + current
constexpr int LH = 12;
constexpr int B  = 4;
constexpr int S  = 1024;
constexpr int D  = 1024;
constexpr int NCH  = 32;        // s-chunks for the scan tails
constexpr int CH   = S / NCH;   // 32
constexpr int DBLK = D / 256;   // 4

// float offsets into workspace (~570 KB used)
constexpr int OFF_Z    = 0;                    // [B*S] per-row softmax denom
constexpr int OFF_ZCUM = B * S;                // [B*S] inclusive prefix over s
constexpr int OFF_CS   = 2 * B * S;            // [B][NCH][D] chunk partial sums
constexpr float EPS = 1e-5f;

typedef float float4n __attribute__((ext_vector_type(4)));

__device__ __forceinline__ float4n ntload4(const float* p) {
    return __builtin_nontemporal_load((const float4n*)p);
}
}

// K1: one WAVE per (b,s) row -- no LDS, no barriers, free-running waves.
// Lane holds 16 row elems (4x float4 at d = lane*4 + j*256). Per layer:
// butterfly-reduce {sum, sumsq, wg-dot} across 64 lanes (shfl_xor, all lanes
// get the total), score = rstd*(sw - mu*swg) + swb, p = exp(score)
// (softmax is shift-invariant; |score| <~ 5 so no max subtraction needed),
// acc += p*v, z += p.  U -> d_out, z -> ws.
// V rows are read ONCE chip-wide -> nontemporal loads keep L2/L3 for U/tails.
__global__ __launch_bounds__(256) void arm_k1(const float* __restrict__ hist,
                                              const float* __restrict__ cur,
                                              const float* __restrict__ w,
                                              const float* __restrict__ gamma,
                                              const float* __restrict__ beta,
                                              float* __restrict__ U,
                                              float* __restrict__ ws) {
    const int tid = threadIdx.x, lane = tid & 63;
    const int gw = blockIdx.x * 4 + (tid >> 6);   // row id = b*S + s, [0, B*S)
    const int d0 = lane * 4;
    const size_t rowoff = (size_t)gw * D;

    // per-wave wg = w*gamma (kept in regs) + swg/swb scalars (butterfly)
    float4n wg[4];
    float swg_p = 0.f, swb_p = 0.f;
#pragma unroll
    for (int j = 0; j < 4; j++) {
        int d = d0 + j * 256;
        float4 wv = *(const float4*)(w + d);
        float4 gv = *(const float4*)(gamma + d);
        float4 bv = *(const float4*)(beta + d);
        wg[j] = (float4n){wv.x * gv.x, wv.y * gv.y, wv.z * gv.z, wv.w * gv.w};
        swg_p += wg[j].x + wg[j].y + wg[j].z + wg[j].w;
        swb_p += wv.x * bv.x + wv.y * bv.y + wv.z * bv.z + wv.w * bv.w;
    }
#pragma unroll
    for (int o = 32; o > 0; o >>= 1) {
        swg_p += __shfl_xor(swg_p, o);
        swb_p += __shfl_xor(swb_p, o);
    }
    const float swg = swg_p, swb = swb_p;

    float4n acc[4] = {{0,0,0,0},{0,0,0,0},{0,0,0,0},{0,0,0,0}};
    float z = 0.f;

#pragma unroll 4
    for (int l = 0; l < L1; l++) {
        const float* row = (l < LH ? hist + (size_t)l * (B * S * D) : cur) + rowoff;
        float4n v[4];
#pragma unroll
        for (int j = 0; j < 4; j++) v[j] = ntload4(row + d0 + j * 256);

        float s1 = 0.f, s2 = 0.f, sw = 0.f;
#pragma unroll
        for (int j = 0; j < 4; j++) {
            s1 += v[j].x + v[j].y + v[j].z + v[j].w;
            s2 += v[j].x * v[j].x + v[j].y * v[j].y + v[j].z * v[j].z + v[j].w * v[j].w;
            sw += wg[j].x * v[j].x + wg[j].y * v[j].y + wg[j].z * v[j].z + wg[j].w * v[j].w;
        }
#pragma unroll
        for (int o = 32; o > 0; o >>= 1) {
            s1 += __shfl_xor(s1, o);
            s2 += __shfl_xor(s2, o);
            sw += __shfl_xor(sw, o);
        }
        float mu   = s1 * (1.0f / D);
        float var  = s2 * (1.0f / D) - mu * mu;
        float rstd = rsqrtf(var + EPS);
        float p = __expf(rstd * (sw - mu * swg) + swb);
#pragma unroll
        for (int j = 0; j < 4; j++) {
            acc[j].x += p * v[j].x; acc[j].y += p * v[j].y;
            acc[j].z += p * v[j].z; acc[j].w += p * v[j].w;
        }
        z += p;
    }

#pragma unroll
    for (int j = 0; j < 4; j++)
        *(float4n*)(U + rowoff + d0 + j * 256) = acc[j];
    if (lane == 0) ws[OFF_Z + gw] = z;
}

// K2: blocks [0, B*NCH*DBLK): per-chunk partial column sums of U.
//     blocks [B*NCH*DBLK, +B): inclusive prefix sum of z over s (one block per b).
__global__ void arm_k2(const float* __restrict__ U, float* __restrict__ ws) {
    int blk = blockIdx.x;
    int tid = threadIdx.x;
    if (blk >= B * NCH * DBLK) {
        int b = blk - B * NCH * DBLK;
        const float* z = ws + OFF_Z + b * S;
        float* zc = ws + OFF_ZCUM + b * S;
        float v[4];
        float loc = 0.f;
#pragma unroll
        for (int j = 0; j < 4; j++) { v[j] = z[tid * 4 + j]; loc += v[j]; }
        __shared__ float lds[256];
        lds[tid] = loc; __syncthreads();
        for (int off = 1; off < 256; off <<= 1) {
            float t = (tid >= off) ? lds[tid - off] : 0.f;
            __syncthreads();
            lds[tid] += t;
            __syncthreads();
        }
        float run = lds[tid] - loc;  // exclusive offset
#pragma unroll
        for (int j = 0; j < 4; j++) { run += v[j]; zc[tid * 4 + j] = run; }
        return;
    }
    int dblk = blk % DBLK;
    int rem = blk / DBLK;
    int ch = rem % NCH, b = rem / NCH;
    int d = dblk * 256 + tid;
    const float* Ub = U + ((size_t)b * S + ch * CH) * D + d;
    float sum = 0.f;
#pragma unroll
    for (int j = 0; j < CH; j++) sum += Ub[(size_t)j * D];
    ws[OFF_CS + (b * NCH + ch) * D + d] = sum;
}

// K3: per (b,ch,dblk): exclusive chunk-prefix from CS (redundant, L2-resident),
// then local cumsum over s within the chunk, divide by Zcum, write h in place.
__global__ void arm_k3(float* __restrict__ U, const float* __restrict__ ws) {
    int blk = blockIdx.x;
    int dblk = blk % DBLK;
    int rem = blk / DBLK;
    int ch = rem % NCH, b = rem / NCH;
    int d = dblk * 256 + threadIdx.x;

    const float* cs = ws + OFF_CS + b * NCH * D + d;
    float run = 0.f;
    for (int c2 = 0; c2 < ch; c2++) run += cs[(size_t)c2 * D];

    const float* zc = ws + OFF_ZCUM + b * S + ch * CH;
    float* Ub = U + ((size_t)b * S + ch * CH) * D + d;
#pragma unroll
    for (int j = 0; j < CH; j++) {
        run += Ub[(size_t)j * D];
        float h = run / zc[j];
        __builtin_nontemporal_store(h, &Ub[(size_t)j * D]);
    }
}

extern "C" void kernel_launch(void* const* d_in, const int* in_sizes, int n_in,
                              void* d_out, int out_size, void* d_ws, size_t ws_size,
                              hipStream_t stream) {
    const float* hist  = (const float*)d_in[0];  // [12,B,S,D]
    const float* cur   = (const float*)d_in[1];  // [B,S,D]
    const float* w     = (const float*)d_in[2];  // [D]
    const float* gamma = (const float*)d_in[3];  // [D]
    const float* beta  = (const float*)d_in[4];  // [D]
    float* out = (float*)d_out;                  // [B,S,D]
    float* ws  = (float*)d_ws;

    arm_k1<<<B * S / 4, 256, 0, stream>>>(hist, cur, w, gamma, beta, out, ws);
    arm_k2<<<B * NCH * DBLK + B, 256, 0, stream>>>(out, ws);
    arm_k3<<<B * NCH * DBLK, 256, 0, stream>>>(out, ws);
}

// Round 9
// 60.590 us; speedup vs baseline: 1.1031x; 1.1031x over previous
//
#include <hip/hip_runtime.h>
#include <math.h>

namespace {
constexpr int L1 = 13;   // 12 history layers + current
constexpr int LH = 12;
constexpr int B  = 4;
constexpr int S  = 1024;
constexpr int D  = 1024;
constexpr int NCH  = 32;        // s-chunks for the scan tails
constexpr int CH   = S / NCH;   // 32 rows per chunk
constexpr int DBLK = D / 256;   // 4
constexpr int RPB  = 8;         // rows per K1 block
constexpr int NPS  = B * S / RPB;  // 512 PS rows

// float offsets into workspace (~2.65 MB used)
constexpr int OFF_Z    = 0;                    // [B*S] per-row softmax denom
constexpr int OFF_ZCUM = B * S;                // [B*S] inclusive prefix over s
constexpr int OFF_CS   = 2 * B * S;            // [B][NCH][D] chunk partial sums
constexpr int OFF_PS   = OFF_CS + B * NCH * D; // [NPS][D] 8-row partial sums
constexpr float EPS = 1e-5f;

typedef float float4n __attribute__((ext_vector_type(4)));
}

// K1: 512 blocks x 4 waves; wave handles 2 adjacent rows (block = 8 consecutive
// rows -> 32 KB contiguous per layer-stream for DRAM locality). Per row: R6's
// barrier-free pipeline: lane holds 16 elems (4x float4), butterfly-reduce
// {sum,sumsq,wg-dot} over 64 lanes, score = rstd*(sw-mu*swg)+swb, p=exp(score)
// (softmax shift-invariant, |score| <~ 5), acc += p*v, z += p. U->d_out, z->ws.
// Wave's 2-row acc sum goes to its private LDS slot; one end barrier reduces
// 4 slots -> PS row (8-row partial), so K2 never re-reads U.
__global__ __launch_bounds__(256) void arm_k1(const float* __restrict__ hist,
                                              const float* __restrict__ cur,
                                              const float* __restrict__ w,
                                              const float* __restrict__ gamma,
                                              const float* __restrict__ beta,
                                              float* __restrict__ U,
                                              float* __restrict__ ws) {
    const int tid = threadIdx.x, lane = tid & 63, wid = tid >> 6;
    const int blk = blockIdx.x;              // [0, 512)
    const int row0 = blk * RPB + wid * 2;    // global row id = b*S + s
    const int d0 = lane * 4;

    __shared__ float cs[4][D];               // 16 KB: per-wave partial slots

    // per-wave wg = w*gamma (regs) + swg/swb scalars (butterfly)
    float4n wg[4];
    float swg_p = 0.f, swb_p = 0.f;
#pragma unroll
    for (int j = 0; j < 4; j++) {
        int d = d0 + j * 256;
        float4n wv = *(const float4n*)(w + d);
        float4n gv = *(const float4n*)(gamma + d);
        float4n bv = *(const float4n*)(beta + d);
        wg[j] = wv * gv;
        swg_p += wg[j].x + wg[j].y + wg[j].z + wg[j].w;
        float4n wb = wv * bv;
        swb_p += wb.x + wb.y + wb.z + wb.w;
    }
#pragma unroll
    for (int o = 32; o > 0; o >>= 1) {
        swg_p += __shfl_xor(swg_p, o);
        swb_p += __shfl_xor(swb_p, o);
    }
    const float swg = swg_p, swb = swb_p;

#pragma unroll
    for (int r = 0; r < 2; r++) {
        const size_t rowoff = (size_t)(row0 + r) * D;
        float4n acc[4] = {{0,0,0,0},{0,0,0,0},{0,0,0,0},{0,0,0,0}};
        float z = 0.f;

#pragma unroll 2
        for (int l = 0; l < L1; l++) {
            const float* row = (l < LH ? hist + (size_t)l * (B * S * D) : cur) + rowoff;
            float4n v[4];
#pragma unroll
            for (int j = 0; j < 4; j++) v[j] = *(const float4n*)(row + d0 + j * 256);

            float s1 = 0.f, s2 = 0.f, sw = 0.f;
#pragma unroll
            for (int j = 0; j < 4; j++) {
                s1 += v[j].x + v[j].y + v[j].z + v[j].w;
                s2 += v[j].x * v[j].x + v[j].y * v[j].y + v[j].z * v[j].z + v[j].w * v[j].w;
                sw += wg[j].x * v[j].x + wg[j].y * v[j].y + wg[j].z * v[j].z + wg[j].w * v[j].w;
            }
#pragma unroll
            for (int o = 32; o > 0; o >>= 1) {
                s1 += __shfl_xor(s1, o);
                s2 += __shfl_xor(s2, o);
                sw += __shfl_xor(sw, o);
            }
            float mu   = s1 * (1.0f / D);
            float var  = s2 * (1.0f / D) - mu * mu;
            float rstd = rsqrtf(var + EPS);
            float p = __expf(rstd * (sw - mu * swg) + swb);
#pragma unroll
            for (int j = 0; j < 4; j++) acc[j] += v[j] * p;
            z += p;
        }

#pragma unroll
        for (int j = 0; j < 4; j++)
            *(float4n*)(U + rowoff + d0 + j * 256) = acc[j];
        if (lane == 0) ws[OFF_Z + row0 + r] = z;

        if (r == 0) {
#pragma unroll
            for (int j = 0; j < 4; j++)
                *(float4n*)&cs[wid][d0 + j * 256] = acc[j];
        } else {
#pragma unroll
            for (int j = 0; j < 4; j++) {
                float4n t = *(float4n*)&cs[wid][d0 + j * 256];
                *(float4n*)&cs[wid][d0 + j * 256] = t + acc[j];
            }
        }
    }

    __syncthreads();
    // reduce 4 wave slots -> PS[blk] (each thread 4 contiguous cols)
    const int c = tid * 4;
    float4n ps = *(float4n*)&cs[0][c];
    ps += *(float4n*)&cs[1][c];
    ps += *(float4n*)&cs[2][c];
    ps += *(float4n*)&cs[3][c];
    *(float4n*)(ws + OFF_PS + (size_t)blk * D + c) = ps;
}

// K2: blocks [0, B*NCH): CS[b][ch][d] = sum of 4 PS rows (L2-hot, 2 MB).
//     blocks [B*NCH, +B): inclusive prefix sum of z over s (one block per b).
__global__ void arm_k2(float* __restrict__ ws) {
    int blk = blockIdx.x;
    int tid = threadIdx.x;
    if (blk >= B * NCH) {
        int b = blk - B * NCH;
        const float* z = ws + OFF_Z + b * S;
        float* zc = ws + OFF_ZCUM + b * S;
        float v[4];
        float loc = 0.f;
#pragma unroll
        for (int j = 0; j < 4; j++) { v[j] = z[tid * 4 + j]; loc += v[j]; }
        __shared__ float lds[256];
        lds[tid] = loc; __syncthreads();
        for (int off = 1; off < 256; off <<= 1) {
            float t = (tid >= off) ? lds[tid - off] : 0.f;
            __syncthreads();
            lds[tid] += t;
            __syncthreads();
        }
        float run = lds[tid] - loc;  // exclusive offset
#pragma unroll
        for (int j = 0; j < 4; j++) { run += v[j]; zc[tid * 4 + j] = run; }
        return;
    }
    int b = blk / NCH, ch = blk % NCH;
    int c = tid * 4;
    float4n s = {0, 0, 0, 0};
#pragma unroll
    for (int k = 0; k < 4; k++)
        s += *(const float4n*)(ws + OFF_PS + (size_t)((b * S / RPB) + ch * 4 + k) * D + c);
    *(float4n*)(ws + OFF_CS + (size_t)blk * D + c) = s;
}

// K3: per (b,ch,dblk): exclusive chunk-prefix from CS (redundant, L2-resident),
// then local cumsum over s within the chunk, divide by Zcum, write h in place.
__global__ void arm_k3(float* __restrict__ U, const float* __restrict__ ws) {
    int blk = blockIdx.x;
    int dblk = blk % DBLK;
    int rem = blk / DBLK;
    int ch = rem % NCH, b = rem / NCH;
    int d = dblk * 256 + threadIdx.x;

    const float* cs = ws + OFF_CS + b * NCH * D + d;
    float run = 0.f;
    for (int c2 = 0; c2 < ch; c2++) run += cs[(size_t)c2 * D];

    const float* zc = ws + OFF_ZCUM + b * S + ch * CH;
    float* Ub = U + ((size_t)b * S + ch * CH) * D + d;
#pragma unroll
    for (int j = 0; j < CH; j++) {
        run += Ub[(size_t)j * D];
        Ub[(size_t)j * D] = run / zc[j];
    }
}

extern "C" void kernel_launch(void* const* d_in, const int* in_sizes, int n_in,
                              void* d_out, int out_size, void* d_ws, size_t ws_size,
                              hipStream_t stream) {
    const float* hist  = (const float*)d_in[0];  // [12,B,S,D]
    const float* cur   = (const float*)d_in[1];  // [B,S,D]
    const float* w     = (const float*)d_in[2];  // [D]
    const float* gamma = (const float*)d_in[3];  // [D]
    const float* beta  = (const float*)d_in[4];  // [D]
    float* out = (float*)d_out;                  // [B,S,D]
    float* ws  = (float*)d_ws;

    arm_k1<<<B * S / RPB, 256, 0, stream>>>(hist, cur, w, gamma, beta, out, ws);
    arm_k2<<<B * NCH + B, 256, 0, stream>>>(ws);
    arm_k3<<<B * NCH * DBLK, 256, 0, stream>>>(out, ws);
}